// Round 1
// baseline (50.180 us; speedup 1.0000x reference)
//
#include <hip/hip_runtime.h>

// OrthogonalMatrixLoss: out = (sum_b sum_{i!=j} (x[b] @ x[b]^T)[i,j]) / B
// Algebraic identity: = (sum_{b,k} (sum_i x[b,i,k])^2 - sum x^2) / B
// => single streaming pass over x, memory-bound.

constexpr int BATCH = 64;
constexpr int DIM   = 1024;
constexpr int ICH   = 8;            // row-chunks per batch
constexpr int ROWS  = DIM / ICH;    // 128 rows per block

__device__ __forceinline__ double block_reduce_sum(double v, double* smem) {
    #pragma unroll
    for (int off = 32; off > 0; off >>= 1) v += __shfl_down(v, off, 64);
    const int lane = threadIdx.x & 63;
    const int w    = threadIdx.x >> 6;
    if (lane == 0) smem[w] = v;
    __syncthreads();
    if (threadIdx.x == 0) v = smem[0] + smem[1] + smem[2] + smem[3];
    return v;  // valid on thread 0 only
}

// Pass 1: partial column sums (fp32) + block-level sum of squares (double).
__global__ __launch_bounds__(256) void ortho_pass1(const float* __restrict__ x,
                                                   float* __restrict__ pcs,
                                                   double* __restrict__ pssq) {
    const int b  = blockIdx.x;   // batch
    const int ic = blockIdx.y;   // row chunk
    const int k4 = threadIdx.x * 4;

    const float* xp = x + (size_t)b * DIM * DIM + (size_t)ic * ROWS * DIM + k4;

    float csx = 0.f, csy = 0.f, csz = 0.f, csw = 0.f;
    float ssq = 0.f;
    #pragma unroll 4
    for (int i = 0; i < ROWS; ++i) {
        const float4 v = *reinterpret_cast<const float4*>(xp + (size_t)i * DIM);
        csx += v.x; csy += v.y; csz += v.z; csw += v.w;
        ssq += v.x * v.x + v.y * v.y + v.z * v.z + v.w * v.w;
    }

    float4 cs = make_float4(csx, csy, csz, csw);
    *reinterpret_cast<float4*>(pcs + ((size_t)b * ICH + ic) * DIM + k4) = cs;

    __shared__ double smem[4];
    const double tot = block_reduce_sum((double)ssq, smem);
    if (threadIdx.x == 0) pssq[b * ICH + ic] = tot;
}

// Pass 2: combine row-chunk partials -> full column sums -> sum of squares per batch.
__global__ __launch_bounds__(256) void ortho_pass2(const float* __restrict__ pcs,
                                                   double* __restrict__ pbatch) {
    const int b  = blockIdx.x;
    const int k4 = threadIdx.x * 4;

    float tx = 0.f, ty = 0.f, tz = 0.f, tw = 0.f;
    #pragma unroll
    for (int ic = 0; ic < ICH; ++ic) {
        const float4 v = *reinterpret_cast<const float4*>(
            pcs + ((size_t)b * ICH + ic) * DIM + k4);
        tx += v.x; ty += v.y; tz += v.z; tw += v.w;
    }
    const double s = (double)tx * tx + (double)ty * ty
                   + (double)tz * tz + (double)tw * tw;

    __shared__ double smem[4];
    const double tot = block_reduce_sum(s, smem);
    if (threadIdx.x == 0) pbatch[b] = tot;
}

// Pass 3: final combine, single block.
__global__ __launch_bounds__(256) void ortho_pass3(const double* __restrict__ pbatch,
                                                   const double* __restrict__ pssq,
                                                   float* __restrict__ out) {
    double v = 0.0;
    for (int i = threadIdx.x; i < BATCH; i += 256) v += pbatch[i];
    double q = 0.0;
    for (int i = threadIdx.x; i < BATCH * ICH; i += 256) q += pssq[i];

    __shared__ double smem[4];
    const double sv = block_reduce_sum(v, smem);
    __syncthreads();
    const double sq = block_reduce_sum(q, smem);
    if (threadIdx.x == 0) out[0] = (float)((sv - sq) / (double)BATCH);
}

extern "C" void kernel_launch(void* const* d_in, const int* in_sizes, int n_in,
                              void* d_out, int out_size, void* d_ws, size_t ws_size,
                              hipStream_t stream) {
    const float* x = (const float*)d_in[0];
    float* out = (float*)d_out;

    // ws layout: [B*ICH*DIM floats pcs | B*ICH doubles pssq | B doubles pbatch]
    float*  pcs    = (float*)d_ws;
    double* pssq   = (double*)((char*)d_ws + sizeof(float) * (size_t)BATCH * ICH * DIM);
    double* pbatch = pssq + BATCH * ICH;

    ortho_pass1<<<dim3(BATCH, ICH), 256, 0, stream>>>(x, pcs, pssq);
    ortho_pass2<<<BATCH, 256, 0, stream>>>(pcs, pbatch);
    ortho_pass3<<<1, 256, 0, stream>>>(pbatch, pssq, out);
}

// Round 3
// 45.741 us; speedup vs baseline: 1.0971x; 1.0971x over previous
//
#include <hip/hip_runtime.h>

// OrthogonalMatrixLoss: out = (sum_{b,k} (sum_i x[b,i,k])^2 - sum x^2) / B
// Two dispatches, no cross-block communication inside a dispatch:
//   main:  256 blocks, each owns (batch, 256-column range) over ALL rows
//          -> per-block double partial (colsum^2 sum minus ssq)
//   final: 1 block reduces 256 doubles.
// Fixed-order sums, no atomics => deterministic.

constexpr int BATCH = 64;
constexpr int DIM   = 1024;
constexpr int KR    = 4;            // column ranges per batch
constexpr int COLS  = DIM / KR;     // 256 columns per block
constexpr int TEAMS = 8;            // 512 threads = 8 waves
constexpr int TROWS = DIM / TEAMS;  // 128 rows per team

__global__ __launch_bounds__(512) void ortho_main(const float* __restrict__ x,
                                                  double* __restrict__ part) {
    const int b    = blockIdx.x / KR;
    const int kr   = blockIdx.x % KR;
    const int lane = threadIdx.x & 63;
    const int team = threadIdx.x >> 6;

    // team t covers rows [t*128, (t+1)*128); lane covers 4 consecutive columns.
    const float* xp = x + (size_t)b * DIM * DIM + (size_t)team * TROWS * DIM
                        + (size_t)kr * COLS + (size_t)lane * 4;

    float csx = 0.f, csy = 0.f, csz = 0.f, csw = 0.f;
    float ssq = 0.f;
    #pragma unroll 8
    for (int i = 0; i < TROWS; ++i) {
        const float4 v = *reinterpret_cast<const float4*>(xp + (size_t)i * DIM);
        csx += v.x; csy += v.y; csz += v.z; csw += v.w;
        ssq += v.x * v.x + v.y * v.y + v.z * v.z + v.w * v.w;
    }

    // Combine the 8 team partial column-sums in LDS.
    __shared__ float sc[TEAMS][COLS];   // 8 KB
    sc[team][lane * 4 + 0] = csx;
    sc[team][lane * 4 + 1] = csy;
    sc[team][lane * 4 + 2] = csz;
    sc[team][lane * 4 + 3] = csw;
    __syncthreads();

    double val = -(double)ssq;          // trace part, subtracted
    if (threadIdx.x < COLS) {           // threads 0..255 each own one column
        float c = 0.f;
        #pragma unroll
        for (int t = 0; t < TEAMS; ++t) c += sc[t][threadIdx.x];
        val += (double)c * (double)c;
    }

    // Block reduction over 512 threads.
    #pragma unroll
    for (int off = 32; off > 0; off >>= 1) val += __shfl_down(val, off, 64);
    __shared__ double sred[TEAMS];
    if (lane == 0) sred[team] = val;
    __syncthreads();
    if (threadIdx.x == 0) {
        double t = 0.0;
        #pragma unroll
        for (int i = 0; i < TEAMS; ++i) t += sred[i];
        part[blockIdx.x] = t;
    }
}

__global__ __launch_bounds__(256) void ortho_final(const double* __restrict__ part,
                                                   float* __restrict__ out) {
    double v = part[threadIdx.x];       // exactly 256 partials
    #pragma unroll
    for (int off = 32; off > 0; off >>= 1) v += __shfl_down(v, off, 64);
    __shared__ double sred[4];
    const int lane = threadIdx.x & 63;
    const int w    = threadIdx.x >> 6;
    if (lane == 0) sred[w] = v;
    __syncthreads();
    if (threadIdx.x == 0)
        out[0] = (float)((sred[0] + sred[1] + sred[2] + sred[3]) / (double)BATCH);
}

extern "C" void kernel_launch(void* const* d_in, const int* in_sizes, int n_in,
                              void* d_out, int out_size, void* d_ws, size_t ws_size,
                              hipStream_t stream) {
    const float* x = (const float*)d_in[0];
    float* out = (float*)d_out;
    double* part = (double*)d_ws;       // 256 doubles

    ortho_main<<<BATCH * KR, 512, 0, stream>>>(x, part);
    ortho_final<<<1, 256, 0, stream>>>(part, out);
}